// Round 1
// baseline (1046.980 us; speedup 1.0000x reference)
//
#include <hip/hip_runtime.h>
#include <math.h>

// Problem constants (from reference): B=2, S=2048, E=1024, NH=4, DH=256
#define Bb  2
#define Ss  2048
#define Ee  1024
#define NHh 4
#define DHh 256
#define BH  (Bb*NHh)      // 8
#define TI  16
#define NT  (Ss/TI)       // 128

// ---------------------------------------------------------------------------
// Kernel 1: gate pre-activations.
// ig[b,h,s] = dot(concat(q,k,v)[b,s,:], igate_w[h,:]) + igate_b[h]; same for fg.
// One block per (b,s); 256 threads reduce 3072-length dots for 4 heads x 2 gates.
// ---------------------------------------------------------------------------
__global__ __launch_bounds__(256) void gates_kernel(
    const float* __restrict__ q, const float* __restrict__ k, const float* __restrict__ v,
    const float* __restrict__ igw, const float* __restrict__ igb,
    const float* __restrict__ fgw, const float* __restrict__ fgb,
    float* __restrict__ ig_out, float* __restrict__ fg_out)
{
    int bs = blockIdx.x;              // 0..B*S-1
    int b = bs / Ss, s = bs % Ss;
    const float* xq = q + (size_t)bs * Ee;
    const float* xk = k + (size_t)bs * Ee;
    const float* xv = v + (size_t)bs * Ee;
    int tid = threadIdx.x;

    float acc[8];
#pragma unroll
    for (int g = 0; g < 8; g++) acc[g] = 0.f;

    for (int c = 0; c < Ee; c += 256) {
        int idx = c + tid;
        float aq = xq[idx], ak = xk[idx], av = xv[idx];
#pragma unroll
        for (int h = 0; h < NHh; h++) {
            const float* wi = igw + (size_t)h * 3 * Ee;
            const float* wf = fgw + (size_t)h * 3 * Ee;
            acc[2*h]   += aq * wi[idx] + ak * wi[Ee + idx] + av * wi[2*Ee + idx];
            acc[2*h+1] += aq * wf[idx] + ak * wf[Ee + idx] + av * wf[2*Ee + idx];
        }
    }
    // wave (64-lane) reduction
#pragma unroll
    for (int g = 0; g < 8; g++) {
        float x = acc[g];
        for (int off = 32; off > 0; off >>= 1) x += __shfl_down(x, off, 64);
        acc[g] = x;
    }
    __shared__ float part[4][8];
    int wid = tid >> 6, lane = tid & 63;
    if (lane == 0) {
#pragma unroll
        for (int g = 0; g < 8; g++) part[wid][g] = acc[g];
    }
    __syncthreads();
    if (tid < 8) {
        float t = part[0][tid] + part[1][tid] + part[2][tid] + part[3][tid];
        int h = tid >> 1;
        size_t o = ((size_t)(b * NHh + h)) * Ss + s;
        if (tid & 1) fg_out[o] = t + fgb[h];
        else         ig_out[o] = t + igb[h];
    }
}

// ---------------------------------------------------------------------------
// Kernel 2: per-(b,h) scans over S.
//   lsig = logsigmoid(fg); cs = inclusive cumsum(lsig); csm1 = cs - lsig (exclusive)
//   a[j] = ig[j] - csm1[j]; M[i] = inclusive running max of a; nf[i] = exp(-cs[i]-M[i])
// One block per (b,h); 256 threads x 8 contiguous elements each.
// ---------------------------------------------------------------------------
#define CHUNK 8
__global__ __launch_bounds__(256) void scan_kernel(
    const float* __restrict__ ig, const float* __restrict__ fg,
    float* __restrict__ a_out, float* __restrict__ M_out, float* __restrict__ nf_out)
{
    int bh = blockIdx.x;
    int tid = threadIdx.x;
    const float* igp = ig + (size_t)bh * Ss;
    const float* fgp = fg + (size_t)bh * Ss;
    int s0 = tid * CHUNK;

    float ls[CHUNK], cs[CHUNK];
    float tot = 0.f;
#pragma unroll
    for (int c = 0; c < CHUNK; c++) {
        float x = fgp[s0 + c];
        float l = fminf(x, 0.f) - log1pf(expf(-fabsf(x)));   // stable logsigmoid
        ls[c] = l; tot += l; cs[c] = tot;
    }
    __shared__ float sc[256];
    sc[tid] = tot; __syncthreads();
    for (int off = 1; off < 256; off <<= 1) {
        float add = (tid >= off) ? sc[tid - off] : 0.f;
        __syncthreads();
        sc[tid] += add;
        __syncthreads();
    }
    float excl = sc[tid] - tot;   // exclusive sum over previous threads' chunks

    float av[CHUNK], pmax[CHUNK];
    float tmax = -INFINITY;
#pragma unroll
    for (int c = 0; c < CHUNK; c++) {
        float csf  = excl + cs[c];        // inclusive cumsum at s0+c
        float csm1 = csf - ls[c];         // exclusive cumsum
        float a = igp[s0 + c] - csm1;
        av[c] = a;
        tmax = fmaxf(tmax, a);
        pmax[c] = tmax;
        cs[c] = csf;
    }
    __shared__ float sm[256];
    sm[tid] = tmax; __syncthreads();
    for (int off = 1; off < 256; off <<= 1) {
        float other = (tid >= off) ? sm[tid - off] : -INFINITY;
        __syncthreads();
        sm[tid] = fmaxf(sm[tid], other);
        __syncthreads();
    }
    float emax = (tid > 0) ? sm[tid - 1] : -INFINITY;
#pragma unroll
    for (int c = 0; c < CHUNK; c++) {
        float M = fmaxf(emax, pmax[c]);
        size_t o = (size_t)bh * Ss + s0 + c;
        a_out[o]  = av[c];
        M_out[o]  = M;
        nf_out[o] = expf(-cs[c] - M);
    }
}

// ---------------------------------------------------------------------------
// Kernel 3: main causal pass. One block per (b,h,i-tile of 16 rows).
// D[i,j] = exp(a[j]-M[i]) (j<=i); C = (q.k/16)*D; accumulate rowsum(C) and C@V.
// Epilogue: normalizer = max(|rowsum|, nf)+EPS, then per-head layernorm + scale.
// ---------------------------------------------------------------------------
__global__ __launch_bounds__(256) void mlstm_main(
    const float* __restrict__ q, const float* __restrict__ k, const float* __restrict__ v,
    const float* __restrict__ a_ws, const float* __restrict__ M_ws, const float* __restrict__ nf_ws,
    const float* __restrict__ out_w, float* __restrict__ out)
{
    int blk  = blockIdx.x;
    int tile = blk % NT;
    int bh   = blk / NT;
    int b = bh / NHh, h = bh % NHh;
    int i0 = tile * TI;
    int tid = threadIdx.x;

    // 260-float row stride: 16B-aligned rows, banks offset by 4 per row (2-way max -> free)
    __shared__ float q_s[TI][260];
    __shared__ float k_s[TI][260];
    __shared__ float v_s[TI][260];
    __shared__ float P_s[TI][17];
    __shared__ float a_j[TI];
    __shared__ float Mi[TI], nfi[TI], rs[TI];
    __shared__ float redS[16][16], redQ[16][16];
    __shared__ float norm_s[TI], mean_s[TI], rstd_s[TI];

    const size_t head_off = (size_t)h * DHh;

    // load q tile: 16 rows x 64 float4
    for (int t = tid; t < TI * 64; t += 256) {
        int r = t >> 6, c4 = t & 63;
        const float4* src = (const float4*)(q + ((size_t)(b * Ss + i0 + r)) * Ee + head_off) + c4;
        *((float4*)&q_s[r][c4 * 4]) = *src;
    }
    if (tid < TI) {
        Mi[tid]  = M_ws[(size_t)bh * Ss + i0 + tid];
        nfi[tid] = nf_ws[(size_t)bh * Ss + i0 + tid];
        rs[tid]  = 0.f;
    }

    const int i_q = tid >> 4;   // QK row
    const int j_q = tid & 15;   // QK col
    const int i_p = tid & 15;   // PV row
    const int dg  = tid >> 4;   // PV d-group
    const int d0  = dg * 16;

    float hacc[16];
#pragma unroll
    for (int dd = 0; dd < 16; dd++) hacc[dd] = 0.f;

    const float inv_sqrt_dh = 0.0625f;  // 1/sqrt(256)

    for (int jt = 0; jt <= tile; jt++) {
        int j0 = jt * TI;
        __syncthreads();   // prior PV readers done before overwriting k_s/v_s
        for (int t = tid; t < TI * 64; t += 256) {
            int r = t >> 6, c4 = t & 63;
            const float4* ks = (const float4*)(k + ((size_t)(b * Ss + j0 + r)) * Ee + head_off) + c4;
            *((float4*)&k_s[r][c4 * 4]) = *ks;
            const float4* vs = (const float4*)(v + ((size_t)(b * Ss + j0 + r)) * Ee + head_off) + c4;
            *((float4*)&v_s[r][c4 * 4]) = *vs;
        }
        if (tid < TI) a_j[tid] = a_ws[(size_t)bh * Ss + j0 + tid];
        __syncthreads();

        // QK: each thread one (i,j) dot of length 256 (float4 LDS reads)
        {
            const float4* qr = (const float4*)&q_s[i_q][0];
            const float4* kr = (const float4*)&k_s[j_q][0];
            float acc = 0.f;
#pragma unroll 8
            for (int c = 0; c < 64; c++) {
                float4 aa = qr[c], bb = kr[c];
                acc += aa.x * bb.x + aa.y * bb.y + aa.z * bb.z + aa.w * bb.w;
            }
            float p = 0.f;
            if (j0 + j_q <= i0 + i_q) {
                p = acc * inv_sqrt_dh * __expf(a_j[j_q] - Mi[i_q]);  // a[j]<=M[i] => exp<=1
            }
            P_s[i_q][j_q] = p;
        }
        __syncthreads();

        if (tid < TI) {     // signed row sums for the |sum C| normalizer
            float ssum = 0.f;
#pragma unroll
            for (int jj = 0; jj < TI; jj++) ssum += P_s[tid][jj];
            rs[tid] += ssum;
        }

        // PV: thread (i_p, dg) accumulates 16 d-elements over 16 j's
#pragma unroll
        for (int jj = 0; jj < TI; jj++) {
            float p = P_s[i_p][jj];
            const float4* vr = (const float4*)&v_s[jj][d0];
            float4 v0 = vr[0], v1 = vr[1], v2 = vr[2], v3 = vr[3];
            hacc[0]  += p * v0.x; hacc[1]  += p * v0.y; hacc[2]  += p * v0.z; hacc[3]  += p * v0.w;
            hacc[4]  += p * v1.x; hacc[5]  += p * v1.y; hacc[6]  += p * v1.z; hacc[7]  += p * v1.w;
            hacc[8]  += p * v2.x; hacc[9]  += p * v2.y; hacc[10] += p * v2.z; hacc[11] += p * v2.w;
            hacc[12] += p * v3.x; hacc[13] += p * v3.y; hacc[14] += p * v3.z; hacc[15] += p * v3.w;
        }
    }
    __syncthreads();
    if (tid < TI) {
        float n = fmaxf(fabsf(rs[tid]), nfi[tid]) + 1e-8f;
        norm_s[tid] = 1.f / n;
    }
    __syncthreads();

    float invn = norm_s[i_p];
    float vals[16];
    float ssum = 0.f, ssq = 0.f;
#pragma unroll
    for (int dd = 0; dd < 16; dd++) {
        float x = hacc[dd] * invn;
        vals[dd] = x; ssum += x; ssq += x * x;
    }
    redS[dg][i_p] = ssum; redQ[dg][i_p] = ssq;
    __syncthreads();
    if (tid < TI) {
        float m = 0.f, qq = 0.f;
#pragma unroll
        for (int g = 0; g < 16; g++) { m += redS[g][tid]; qq += redQ[g][tid]; }
        float mean = m * (1.f / DHh);
        float var  = qq * (1.f / DHh) - mean * mean;
        mean_s[tid] = mean;
        rstd_s[tid] = rsqrtf(var + 1e-5f);
    }
    __syncthreads();
    {
        float mean = mean_s[i_p], rstd = rstd_s[i_p];
        size_t obase = ((size_t)(b * Ss + i0 + i_p)) * Ee + head_off + d0;
        const float* ow = out_w + head_off + d0;
#pragma unroll
        for (int c = 0; c < 4; c++) {
            float4 w4 = *((const float4*)(ow + 4 * c));
            float4 o;
            o.x = (vals[4*c+0] - mean) * rstd * (1.f + w4.x);
            o.y = (vals[4*c+1] - mean) * rstd * (1.f + w4.y);
            o.z = (vals[4*c+2] - mean) * rstd * (1.f + w4.z);
            o.w = (vals[4*c+3] - mean) * rstd * (1.f + w4.w);
            *((float4*)(out + obase + 4 * c)) = o;
        }
    }
}

// ---------------------------------------------------------------------------
extern "C" void kernel_launch(void* const* d_in, const int* in_sizes, int n_in,
                              void* d_out, int out_size, void* d_ws, size_t ws_size,
                              hipStream_t stream) {
    const float* q   = (const float*)d_in[0];
    const float* k   = (const float*)d_in[1];
    const float* v   = (const float*)d_in[2];
    const float* igw = (const float*)d_in[3];
    const float* igb = (const float*)d_in[4];
    const float* fgw = (const float*)d_in[5];
    const float* fgb = (const float*)d_in[6];
    const float* ow  = (const float*)d_in[7];
    float* out = (float*)d_out;

    float* ws = (float*)d_ws;
    float* ig = ws;                 // BH*S = 16384 floats each
    float* fg = ws + 16384;
    float* aa = ws + 32768;
    float* MM = ws + 49152;
    float* nf = ws + 65536;

    gates_kernel<<<Bb * Ss, 256, 0, stream>>>(q, k, v, igw, igb, fgw, fgb, ig, fg);
    scan_kernel<<<BH, 256, 0, stream>>>(ig, fg, aa, MM, nf);
    mlstm_main<<<BH * NT, 256, 0, stream>>>(q, k, v, aa, MM, nf, ow, out);
}

// Round 2
// 370.783 us; speedup vs baseline: 2.8237x; 2.8237x over previous
//
#include <hip/hip_runtime.h>
#include <hip/hip_bf16.h>
#include <math.h>

// Problem constants: B=2, S=2048, E=1024, NH=4, DH=256
#define Bb  2
#define Ss  2048
#define Ee  1024
#define NHh 4
#define DHh 256
#define BH  (Bb*NHh)      // 8
#define TI  32            // i-rows per block
#define TJ  32            // j-cols per iteration

typedef short        s8v   __attribute__((ext_vector_type(8)));   // 8 bf16 (A/B frag)
typedef float        f4v   __attribute__((ext_vector_type(4)));   // 16x16 acc
typedef float        f16v  __attribute__((ext_vector_type(16)));  // 32x32 acc
typedef unsigned int u4v   __attribute__((ext_vector_type(4)));   // 16B LDS write
typedef unsigned short u16x4 __attribute__((ext_vector_type(4))); // 8B LDS write

// RNE fp32 pair -> packed bf16x2
__device__ inline unsigned pkbf2(float a, float b) {
    unsigned ua = __float_as_uint(a), ub = __float_as_uint(b);
    ua = (ua + 0x7FFFu + ((ua >> 16) & 1u)) >> 16;
    ub = (ub + 0x7FFFu + ((ub >> 16) & 1u)) & 0xFFFF0000u;
    return ua | ub;
}

// ---------------------------------------------------------------------------
// Kernel 1: gate pre-activations (unchanged from R0 — not the bottleneck yet)
// ---------------------------------------------------------------------------
__global__ __launch_bounds__(256) void gates_kernel(
    const float* __restrict__ q, const float* __restrict__ k, const float* __restrict__ v,
    const float* __restrict__ igw, const float* __restrict__ igb,
    const float* __restrict__ fgw, const float* __restrict__ fgb,
    float* __restrict__ ig_out, float* __restrict__ fg_out)
{
    int bs = blockIdx.x;
    int b = bs / Ss, s = bs % Ss;
    const float* xq = q + (size_t)bs * Ee;
    const float* xk = k + (size_t)bs * Ee;
    const float* xv = v + (size_t)bs * Ee;
    int tid = threadIdx.x;

    float acc[8];
#pragma unroll
    for (int g = 0; g < 8; g++) acc[g] = 0.f;

    for (int c = 0; c < Ee; c += 256) {
        int idx = c + tid;
        float aq = xq[idx], ak = xk[idx], av = xv[idx];
#pragma unroll
        for (int h = 0; h < NHh; h++) {
            const float* wi = igw + (size_t)h * 3 * Ee;
            const float* wf = fgw + (size_t)h * 3 * Ee;
            acc[2*h]   += aq * wi[idx] + ak * wi[Ee + idx] + av * wi[2*Ee + idx];
            acc[2*h+1] += aq * wf[idx] + ak * wf[Ee + idx] + av * wf[2*Ee + idx];
        }
    }
#pragma unroll
    for (int g = 0; g < 8; g++) {
        float x = acc[g];
        for (int off = 32; off > 0; off >>= 1) x += __shfl_down(x, off, 64);
        acc[g] = x;
    }
    __shared__ float part[4][8];
    int wid = tid >> 6, lane = tid & 63;
    if (lane == 0) {
#pragma unroll
        for (int g = 0; g < 8; g++) part[wid][g] = acc[g];
    }
    __syncthreads();
    if (tid < 8) {
        float t = part[0][tid] + part[1][tid] + part[2][tid] + part[3][tid];
        int h = tid >> 1;
        size_t o = ((size_t)(b * NHh + h)) * Ss + s;
        if (tid & 1) fg_out[o] = t + fgb[h];
        else         ig_out[o] = t + igb[h];
    }
}

// ---------------------------------------------------------------------------
// Kernel 2: per-(b,h) scans (unchanged)
// ---------------------------------------------------------------------------
#define CHUNK 8
__global__ __launch_bounds__(256) void scan_kernel(
    const float* __restrict__ ig, const float* __restrict__ fg,
    float* __restrict__ a_out, float* __restrict__ M_out, float* __restrict__ nf_out)
{
    int bh = blockIdx.x;
    int tid = threadIdx.x;
    const float* igp = ig + (size_t)bh * Ss;
    const float* fgp = fg + (size_t)bh * Ss;
    int s0 = tid * CHUNK;

    float ls[CHUNK], cs[CHUNK];
    float tot = 0.f;
#pragma unroll
    for (int c = 0; c < CHUNK; c++) {
        float x = fgp[s0 + c];
        float l = fminf(x, 0.f) - log1pf(expf(-fabsf(x)));
        ls[c] = l; tot += l; cs[c] = tot;
    }
    __shared__ float sc[256];
    sc[tid] = tot; __syncthreads();
    for (int off = 1; off < 256; off <<= 1) {
        float add = (tid >= off) ? sc[tid - off] : 0.f;
        __syncthreads();
        sc[tid] += add;
        __syncthreads();
    }
    float excl = sc[tid] - tot;

    float av[CHUNK], pmax[CHUNK];
    float tmax = -INFINITY;
#pragma unroll
    for (int c = 0; c < CHUNK; c++) {
        float csf  = excl + cs[c];
        float csm1 = csf - ls[c];
        float a = igp[s0 + c] - csm1;
        av[c] = a;
        tmax = fmaxf(tmax, a);
        pmax[c] = tmax;
        cs[c] = csf;
    }
    __shared__ float sm[256];
    sm[tid] = tmax; __syncthreads();
    for (int off = 1; off < 256; off <<= 1) {
        float other = (tid >= off) ? sm[tid - off] : -INFINITY;
        __syncthreads();
        sm[tid] = fmaxf(sm[tid], other);
        __syncthreads();
    }
    float emax = (tid > 0) ? sm[tid - 1] : -INFINITY;
#pragma unroll
    for (int c = 0; c < CHUNK; c++) {
        float M = fmaxf(emax, pmax[c]);
        size_t o = (size_t)bh * Ss + s0 + c;
        a_out[o]  = av[c];
        M_out[o]  = M;
        nf_out[o] = expf(-cs[c] - M);
    }
}

// ---------------------------------------------------------------------------
// Kernel 3: MFMA flash pass.
// Per block: one (bh, 32-row i-tile). S^T = K·Q^T via mfma 16x16x32 (C-layout
// packs directly into PV A-frag layout). PV via mfma 32x32x16 with V^T in LDS.
// ---------------------------------------------------------------------------
__global__ __launch_bounds__(256, 3) void mlstm_main(
    const float* __restrict__ qp, const float* __restrict__ kp, const float* __restrict__ vp,
    const float* __restrict__ a_ws, const float* __restrict__ M_ws, const float* __restrict__ nf_ws,
    const float* __restrict__ out_w, float* __restrict__ out)
{
    // blockIdx -> (bh, T) bijection; consecutive AND stride-256 pairs sum to
    // constant work (hedges either dispatch->CU pattern).
    int bidx = blockIdx.x;
    int m4 = (bidx >> 1) & 15;
    int f  = ((bidx >> 8) & 1) ? (31 - 2 * m4) : (2 * m4);
    int T  = (bidx & 1) ? (63 - f) : f;            // 0..63
    int bh = (bidx >> 5) & 7;
    int b = bh >> 2, h = bh & 3;
    int I0 = T * TI;
    int tid = threadIdx.x;

    __shared__ union SU {
        struct {
            unsigned short K[32][264];    // bf16 K tile, row stride 528B = 33 wide-banks
            unsigned short Vt[256][40];   // bf16 V^T tile, row stride 80B = 5 wide-banks
            unsigned short P[32][40];     // bf16 P tile (i-major)
        } s;
        float Hs[32][260];                // fp32 H for epilogue (reuses same LDS)
    } su;
    __shared__ float a_s[TJ];
    __shared__ float rs_s[2][TI];
    __shared__ float inv_s[TI], mean_s[TI], rstd_s[TI];

    const int w    = tid >> 6;     // wave 0..3
    const int lane = tid & 63;
    const int jh = w & 1, ih = w >> 1;      // QK: wave = (j-half, i-half)
    const int lm = lane & 15, q4 = lane >> 4;
    const int m5 = lane & 31, hl = lane >> 5;

    const size_t hoff = (size_t)h * DHh;

    // ---- Q fragments cached in registers (B-operand of S^T = K·Q^T) ----
    // lane n = lm -> Q row I0 + ih*16 + lm; k = ks*32 + q4*8 + 0..7
    s8v qf[8];
    {
        const float* qrow = qp + ((size_t)(b * Ss + I0 + ih * 16 + lm)) * Ee + hoff;
#pragma unroll
        for (int ks = 0; ks < 8; ks++) {
            const float4* p = (const float4*)(qrow + ks * 32 + q4 * 8);
            float4 x0 = p[0], x1 = p[1];
            union { s8v v; unsigned u[4]; } r;
            r.u[0] = pkbf2(x0.x, x0.y);
            r.u[1] = pkbf2(x0.z, x0.w);
            r.u[2] = pkbf2(x1.x, x1.y);
            r.u[3] = pkbf2(x1.z, x1.w);
            qf[ks] = r.v;
        }
    }
    // decay row-max for this lane's i (C-layout: col n = lm = i)
    const float Mi = M_ws[(size_t)bh * Ss + I0 + ih * 16 + lm];

    f16v acc0, acc1;
#pragma unroll
    for (int i = 0; i < 16; i++) { acc0[i] = 0.f; acc1[i] = 0.f; }
    float rs_acc = 0.f;

    const float inv_sqrt_dh = 0.0625f;

    for (int jt = 0; jt <= T; jt++) {
        const int J0 = jt * TJ;
        __syncthreads();   // prior iteration's PV reads of Vt/P done

        // ---- stage K tile (rows j, bf16) ----
        {
            int r = tid >> 3, c0 = (tid & 7) * 32;
            const float* src = kp + ((size_t)(b * Ss + J0 + r)) * Ee + hoff + c0;
            float4 x[8];
#pragma unroll
            for (int i = 0; i < 8; i++) x[i] = ((const float4*)src)[i];
#pragma unroll
            for (int i = 0; i < 4; i++) {
                u4v wv;
                wv.x = pkbf2(x[2*i].x,   x[2*i].y);
                wv.y = pkbf2(x[2*i].z,   x[2*i].w);
                wv.z = pkbf2(x[2*i+1].x, x[2*i+1].y);
                wv.w = pkbf2(x[2*i+1].z, x[2*i+1].w);
                *(u4v*)&su.s.K[r][c0 + 8 * i] = wv;
            }
        }
        // ---- stage V^T tile: thread -> (d-pair, j-half) ----
        {
            int dd = 2 * (tid & 127), jh2 = tid >> 7;
            const float* vbase = vp + ((size_t)(b * Ss + J0 + jh2 * 16)) * Ee + hoff + dd;
            float c0[16], c1[16];
#pragma unroll
            for (int jj = 0; jj < 16; jj++) {
                float2 xx = *(const float2*)(vbase + (size_t)jj * Ee);
                c0[jj] = xx.x; c1[jj] = xx.y;
            }
#pragma unroll
            for (int e = 0; e < 2; e++) {
                const float* cc = e ? c1 : c0;
#pragma unroll
                for (int half = 0; half < 2; half++) {
                    u4v wv;
                    wv.x = pkbf2(cc[8*half+0], cc[8*half+1]);
                    wv.y = pkbf2(cc[8*half+2], cc[8*half+3]);
                    wv.z = pkbf2(cc[8*half+4], cc[8*half+5]);
                    wv.w = pkbf2(cc[8*half+6], cc[8*half+7]);
                    *(u4v*)&su.s.Vt[dd + e][jh2 * 16 + 8 * half] = wv;
                }
            }
        }
        if (tid < TJ) a_s[tid] = a_ws[(size_t)bh * Ss + J0 + tid];
        __syncthreads();

        // ---- QK: S^T tile [16j x 16i] per wave via mfma 16x16x32 ----
        f4v c = {0.f, 0.f, 0.f, 0.f};
#pragma unroll
        for (int ks = 0; ks < 8; ks++) {
            s8v af = *(const s8v*)&su.s.K[jh * 16 + lm][ks * 32 + q4 * 8];
            c = __builtin_amdgcn_mfma_f32_16x16x32_bf16(af, qf[ks], c, 0, 0, 0);
        }
        // decay + mask + pack P (C-layout: col = i = lm, rows = j = q4*4 + r)
        {
            const int jb = jh * 16 + q4 * 4;
            const int ig = I0 + ih * 16 + lm;
            float p[4];
            float rsum = 0.f;
#pragma unroll
            for (int r = 0; r < 4; r++) {
                int jg = J0 + jb + r;
                float pv = 0.f;
                if (jg <= ig) pv = c[r] * inv_sqrt_dh * __expf(a_s[jb + r] - Mi);
                p[r] = pv; rsum += pv;
            }
            union { u16x4 v; unsigned short u[4]; } pw;
            pw.u[0] = (unsigned short)(pkbf2(p[0], p[1]) & 0xFFFFu);
            pw.u[1] = (unsigned short)(pkbf2(p[0], p[1]) >> 16);
            pw.u[2] = (unsigned short)(pkbf2(p[2], p[3]) & 0xFFFFu);
            pw.u[3] = (unsigned short)(pkbf2(p[2], p[3]) >> 16);
            *(u16x4*)&su.s.P[ih * 16 + lm][jb] = pw.v;
            // rowsum across the 4 quads sharing this i
            rsum += __shfl_xor(rsum, 16);
            rsum += __shfl_xor(rsum, 32);
            rs_acc += rsum;
        }
        __syncthreads();

        // ---- PV: H[32 x 256] += P[32 x 32] · V[32 x 256] via mfma 32x32x16 ----
        const int n0 = w * 64;
#pragma unroll
        for (int ks2 = 0; ks2 < 32; ks2 += 16) {
            s8v pa  = *(const s8v*)&su.s.P[m5][ks2 + hl * 8];
            s8v vb0 = *(const s8v*)&su.s.Vt[n0 + m5][ks2 + hl * 8];
            s8v vb1 = *(const s8v*)&su.s.Vt[n0 + 32 + m5][ks2 + hl * 8];
            acc0 = __builtin_amdgcn_mfma_f32_32x32x16_bf16(pa, vb0, acc0, 0, 0, 0);
            acc1 = __builtin_amdgcn_mfma_f32_32x32x16_bf16(pa, vb1, acc1, 0, 0, 0);
        }
    }

    // ---- epilogue: normalizer, group-norm, output ----
    if (lane < 16) rs_s[jh][ih * 16 + lm] = rs_acc;
    __syncthreads();
    if (tid < TI) {
        float r = rs_s[0][tid] + rs_s[1][tid];
        float nfv = nf_ws[(size_t)bh * Ss + I0 + tid];
        float n = fmaxf(fabsf(r), nfv) + 1e-8f;
        inv_s[tid] = 1.f / n;
    }
    __syncthreads();   // also guarantees all PV LDS reads done before Hs overwrite

    // dump normalized H to LDS fp32 (32x32 C-layout: col = m5, row = f(reg,hl))
#pragma unroll
    for (int nt = 0; nt < 2; nt++) {
#pragma unroll
        for (int r = 0; r < 16; r++) {
            int m = (r & 3) + 8 * (r >> 2) + 4 * hl;
            float x = (nt ? acc1[r] : acc0[r]) * inv_s[m];
            su.Hs[m][w * 64 + nt * 32 + m5] = x;
        }
    }
    __syncthreads();

    // group-norm over DH=256 per row
    {
        int i = tid >> 3, seg = tid & 7;
        float sx = 0.f, sq = 0.f;
#pragma unroll
        for (int c4 = 0; c4 < 8; c4++) {
            float4 hv = *(const float4*)&su.Hs[i][seg * 32 + c4 * 4];
            sx += hv.x + hv.y + hv.z + hv.w;
            sq += hv.x*hv.x + hv.y*hv.y + hv.z*hv.z + hv.w*hv.w;
        }
        sx += __shfl_xor(sx, 1); sq += __shfl_xor(sq, 1);
        sx += __shfl_xor(sx, 2); sq += __shfl_xor(sq, 2);
        sx += __shfl_xor(sx, 4); sq += __shfl_xor(sq, 4);
        if (seg == 0) {
            float mean = sx * (1.f / DHh);
            float var  = sq * (1.f / DHh) - mean * mean;
            mean_s[i] = mean;
            rstd_s[i] = rsqrtf(var + 1e-5f);
        }
    }
    __syncthreads();
    {
        int i = tid >> 3, seg = tid & 7;
        float mean = mean_s[i], rstd = rstd_s[i];
        float* orow = out + ((size_t)(b * Ss + I0 + i)) * Ee + hoff;
        const float* ow = out_w + hoff;
#pragma unroll
        for (int c4 = 0; c4 < 8; c4++) {
            int d = seg * 32 + c4 * 4;
            float4 hv = *(const float4*)&su.Hs[i][d];
            float4 w4 = *(const float4*)&ow[d];
            float4 o;
            o.x = (hv.x - mean) * rstd * (1.f + w4.x);
            o.y = (hv.y - mean) * rstd * (1.f + w4.y);
            o.z = (hv.z - mean) * rstd * (1.f + w4.z);
            o.w = (hv.w - mean) * rstd * (1.f + w4.w);
            *(float4*)(orow + d) = o;
        }
    }
}

// ---------------------------------------------------------------------------
extern "C" void kernel_launch(void* const* d_in, const int* in_sizes, int n_in,
                              void* d_out, int out_size, void* d_ws, size_t ws_size,
                              hipStream_t stream) {
    const float* q   = (const float*)d_in[0];
    const float* k   = (const float*)d_in[1];
    const float* v   = (const float*)d_in[2];
    const float* igw = (const float*)d_in[3];
    const float* igb = (const float*)d_in[4];
    const float* fgw = (const float*)d_in[5];
    const float* fgb = (const float*)d_in[6];
    const float* ow  = (const float*)d_in[7];
    float* out = (float*)d_out;

    float* ws = (float*)d_ws;
    float* ig = ws;                 // BH*S = 16384 floats each
    float* fg = ws + 16384;
    float* aa = ws + 32768;
    float* MM = ws + 49152;
    float* nf = ws + 65536;

    gates_kernel<<<Bb * Ss, 256, 0, stream>>>(q, k, v, igw, igb, fgw, fgb, ig, fg);
    scan_kernel<<<BH, 256, 0, stream>>>(ig, fg, aa, MM, nf);
    mlstm_main<<<512, 256, 0, stream>>>(q, k, v, aa, MM, nf, ow, out);
}

// Round 4
// 253.965 us; speedup vs baseline: 4.1225x; 1.4600x over previous
//
#include <hip/hip_runtime.h>
#include <hip/hip_bf16.h>
#include <math.h>

// Problem constants: B=2, S=2048, E=1024, NH=4, DH=256
#define Bb  2
#define Ss  2048
#define Ee  1024
#define NHh 4
#define DHh 256
#define BH  (Bb*NHh)      // 8
#define TI  32            // i-rows per block
#define TJ  32            // j-cols per iteration

typedef short        s8v   __attribute__((ext_vector_type(8)));   // 8 bf16 (A/B frag)
typedef float        f4v   __attribute__((ext_vector_type(4)));   // 16x16 acc
typedef float        f16v  __attribute__((ext_vector_type(16)));  // 32x32 acc
typedef unsigned int u4v   __attribute__((ext_vector_type(4)));   // 16B LDS write
typedef unsigned short u16x4 __attribute__((ext_vector_type(4))); // 8B LDS write

// fp32 pair -> packed bf16x2 via HW v_cvt_pk_bf16_f32 (a = low 16)
__device__ inline unsigned pkbf2(float a, float b) {
    __hip_bfloat162 h2 = __float22bfloat162_rn(float2{a, b});
    unsigned u;
    __builtin_memcpy(&u, &h2, 4);
    return u;
}

// ---------------------------------------------------------------------------
// Kernel 1: gate pre-activations, float4 version (one c-pass, 27 vec loads/thr)
// ---------------------------------------------------------------------------
__global__ __launch_bounds__(256) void gates_kernel(
    const float* __restrict__ q, const float* __restrict__ k, const float* __restrict__ v,
    const float* __restrict__ igw, const float* __restrict__ igb,
    const float* __restrict__ fgw, const float* __restrict__ fgb,
    float* __restrict__ ig_out, float* __restrict__ fg_out)
{
    int bs = blockIdx.x;
    int b = bs / Ss, s = bs % Ss;
    int tid = threadIdx.x;
    int c4 = tid * 4;                       // 256 threads x 4 = Ee
    float4 aq = *(const float4*)(q + (size_t)bs * Ee + c4);
    float4 ak = *(const float4*)(k + (size_t)bs * Ee + c4);
    float4 av = *(const float4*)(v + (size_t)bs * Ee + c4);

    float acc[8];
#pragma unroll
    for (int h = 0; h < NHh; h++) {
        const float* wi = igw + (size_t)h * 3 * Ee;
        const float* wf = fgw + (size_t)h * 3 * Ee;
        float4 wq, wk, wv;
        wq = *(const float4*)(wi + c4);
        wk = *(const float4*)(wi + Ee + c4);
        wv = *(const float4*)(wi + 2*Ee + c4);
        acc[2*h] = aq.x*wq.x + aq.y*wq.y + aq.z*wq.z + aq.w*wq.w
                 + ak.x*wk.x + ak.y*wk.y + ak.z*wk.z + ak.w*wk.w
                 + av.x*wv.x + av.y*wv.y + av.z*wv.z + av.w*wv.w;
        wq = *(const float4*)(wf + c4);
        wk = *(const float4*)(wf + Ee + c4);
        wv = *(const float4*)(wf + 2*Ee + c4);
        acc[2*h+1] = aq.x*wq.x + aq.y*wq.y + aq.z*wq.z + aq.w*wq.w
                   + ak.x*wk.x + ak.y*wk.y + ak.z*wk.z + ak.w*wk.w
                   + av.x*wv.x + av.y*wv.y + av.z*wv.z + av.w*wv.w;
    }
#pragma unroll
    for (int g = 0; g < 8; g++) {
        float x = acc[g];
        for (int off = 32; off > 0; off >>= 1) x += __shfl_down(x, off, 64);
        acc[g] = x;
    }
    __shared__ float part[4][8];
    int wid = tid >> 6, lane = tid & 63;
    if (lane == 0) {
#pragma unroll
        for (int g = 0; g < 8; g++) part[wid][g] = acc[g];
    }
    __syncthreads();
    if (tid < 8) {
        float t = part[0][tid] + part[1][tid] + part[2][tid] + part[3][tid];
        int h = tid >> 1;
        size_t o = ((size_t)(b * NHh + h)) * Ss + s;
        if (tid & 1) fg_out[o] = t + fgb[h];
        else         ig_out[o] = t + igb[h];
    }
}

// ---------------------------------------------------------------------------
// Kernel 2: per-(b,h) scans (unchanged)
// ---------------------------------------------------------------------------
#define CHUNK 8
__global__ __launch_bounds__(256) void scan_kernel(
    const float* __restrict__ ig, const float* __restrict__ fg,
    float* __restrict__ a_out, float* __restrict__ M_out, float* __restrict__ nf_out)
{
    int bh = blockIdx.x;
    int tid = threadIdx.x;
    const float* igp = ig + (size_t)bh * Ss;
    const float* fgp = fg + (size_t)bh * Ss;
    int s0 = tid * CHUNK;

    float ls[CHUNK], cs[CHUNK];
    float tot = 0.f;
#pragma unroll
    for (int c = 0; c < CHUNK; c++) {
        float x = fgp[s0 + c];
        float l = fminf(x, 0.f) - log1pf(expf(-fabsf(x)));
        ls[c] = l; tot += l; cs[c] = tot;
    }
    __shared__ float sc[256];
    sc[tid] = tot; __syncthreads();
    for (int off = 1; off < 256; off <<= 1) {
        float add = (tid >= off) ? sc[tid - off] : 0.f;
        __syncthreads();
        sc[tid] += add;
        __syncthreads();
    }
    float excl = sc[tid] - tot;

    float av[CHUNK], pmax[CHUNK];
    float tmax = -INFINITY;
#pragma unroll
    for (int c = 0; c < CHUNK; c++) {
        float csf  = excl + cs[c];
        float csm1 = csf - ls[c];
        float a = igp[s0 + c] - csm1;
        av[c] = a;
        tmax = fmaxf(tmax, a);
        pmax[c] = tmax;
        cs[c] = csf;
    }
    __shared__ float sm[256];
    sm[tid] = tmax; __syncthreads();
    for (int off = 1; off < 256; off <<= 1) {
        float other = (tid >= off) ? sm[tid - off] : -INFINITY;
        __syncthreads();
        sm[tid] = fmaxf(sm[tid], other);
        __syncthreads();
    }
    float emax = (tid > 0) ? sm[tid - 1] : -INFINITY;
#pragma unroll
    for (int c = 0; c < CHUNK; c++) {
        float M = fmaxf(emax, pmax[c]);
        size_t o = (size_t)bh * Ss + s0 + c;
        a_out[o]  = av[c];
        M_out[o]  = M;
        nf_out[o] = expf(-cs[c] - M);
    }
}

// ---------------------------------------------------------------------------
// Kernel 3: MFMA flash pass. SPLIT=true: each (bh,T) i-tile's j-range split in
// 2 balanced segments across 2 blocks writing fp32 partials (seg0 -> outF,
// seg1 -> Hpart) + rowsums. SPLIT=false: single block per i-tile, full epilogue.
// ---------------------------------------------------------------------------
template<bool SPLIT>
__global__ __launch_bounds__(256, 3) void mlstm_main(
    const float* __restrict__ qp, const float* __restrict__ kp, const float* __restrict__ vp,
    const float* __restrict__ a_ws, const float* __restrict__ M_ws, const float* __restrict__ nf_ws,
    const float* __restrict__ out_w, float* __restrict__ outF,
    float* __restrict__ Hpart, float* __restrict__ rsbuf)
{
    int bidx = blockIdx.x;
    int seg = 0, bh, T;
    if (SPLIT) {
        seg = bidx & 1;
        bh  = (bidx >> 1) & 7;
        T   = 63 - (bidx >> 4);          // heaviest-first (LPT scheduling)
    } else {
        int m4 = (bidx >> 1) & 15;
        int f  = ((bidx >> 8) & 1) ? (31 - 2 * m4) : (2 * m4);
        T  = (bidx & 1) ? (63 - f) : f;
        bh = (bidx >> 5) & 7;
    }
    int b = bh >> 2, h = bh & 3;
    int I0 = T * TI;
    int tid = threadIdx.x;

    int len = T + 1;
    int jt_beg = 0, jt_end = len;
    if (SPLIT) {
        int n0 = (len + 1) >> 1;
        jt_beg = seg ? n0 : 0;
        jt_end = seg ? len : n0;
    }
    const size_t hoff = (size_t)h * DHh;
    float* Hdst = (SPLIT && seg) ? Hpart : outF;

    if (SPLIT && jt_beg >= jt_end) {      // empty segment: zero partials
        float4 z = {0.f, 0.f, 0.f, 0.f};
        for (int t = tid; t < TI * 64; t += 256) {
            int r = t >> 6, c = t & 63;
            *(float4*)(Hdst + ((size_t)(b * Ss + I0 + r)) * Ee + hoff + 4 * c) = z;
        }
        if (tid < TI) rsbuf[(size_t)seg * BH * Ss + (size_t)bh * Ss + I0 + tid] = 0.f;
        return;
    }

    __shared__ union SU {
        struct {
            unsigned short K[32][264];    // bf16 K tile
            unsigned short Vt[256][40];   // bf16 V^T tile
            unsigned short P[32][40];     // bf16 P tile (i-major)
        } s;
        float Hs[32][260];                // fp32 H for epilogue (reuses LDS)
    } su;
    __shared__ float a_s[TJ];
    __shared__ float rs_s[2][TI];
    __shared__ float inv_s[TI], mean_s[TI], rstd_s[TI];

    const int w    = tid >> 6;
    const int lane = tid & 63;
    const int jh = w & 1, ih = w >> 1;
    const int lm = lane & 15, q4 = lane >> 4;
    const int m5 = lane & 31, hl = lane >> 5;

    // ---- Q fragments cached in registers (B-operand of S^T = K·Q^T) ----
    s8v qf[8];
    {
        const float* qrow = qp + ((size_t)(b * Ss + I0 + ih * 16 + lm)) * Ee + hoff;
#pragma unroll
        for (int ks = 0; ks < 8; ks++) {
            const float4* p = (const float4*)(qrow + ks * 32 + q4 * 8);
            float4 x0 = p[0], x1 = p[1];
            union { s8v v; unsigned u[4]; } r;
            r.u[0] = pkbf2(x0.x, x0.y);
            r.u[1] = pkbf2(x0.z, x0.w);
            r.u[2] = pkbf2(x1.x, x1.y);
            r.u[3] = pkbf2(x1.z, x1.w);
            qf[ks] = r.v;
        }
    }
    const float Mi = M_ws[(size_t)bh * Ss + I0 + ih * 16 + lm];

    f16v acc0, acc1;
#pragma unroll
    for (int i = 0; i < 16; i++) { acc0[i] = 0.f; acc1[i] = 0.f; }
    float rs_acc = 0.f;

    const float inv_sqrt_dh = 0.0625f;
    const int kr = tid >> 3, kc0 = tid & 7;   // K staging: row, chunk group

    for (int jt = jt_beg; jt < jt_end; jt++) {
        const int J0 = jt * TJ;
        __syncthreads();

        // ---- stage K tile: thread owns stride-8 chunks (bank-conflict-free) ----
        {
            const float* src = kp + ((size_t)(b * Ss + J0 + kr)) * Ee + hoff;
#pragma unroll
            for (int i = 0; i < 4; i++) {
                int ch = kc0 + 8 * i;                 // 16B bf16 chunk index
                float4 x0 = *(const float4*)(src + 8 * ch);
                float4 x1 = *(const float4*)(src + 8 * ch + 4);
                u4v wv;
                wv.x = pkbf2(x0.x, x0.y);
                wv.y = pkbf2(x0.z, x0.w);
                wv.z = pkbf2(x1.x, x1.y);
                wv.w = pkbf2(x1.z, x1.w);
                *(u4v*)&su.s.K[kr][8 * ch] = wv;
            }
        }
        // ---- stage V^T tile ----
        {
            int dd = 2 * (tid & 127), jh2 = tid >> 7;
            const float* vbase = vp + ((size_t)(b * Ss + J0 + jh2 * 16)) * Ee + hoff + dd;
            float c0[16], c1[16];
#pragma unroll
            for (int jj = 0; jj < 16; jj++) {
                float2 xx = *(const float2*)(vbase + (size_t)jj * Ee);
                c0[jj] = xx.x; c1[jj] = xx.y;
            }
#pragma unroll
            for (int e = 0; e < 2; e++) {
                const float* cc = e ? c1 : c0;
#pragma unroll
                for (int half = 0; half < 2; half++) {
                    u4v wv;
                    wv.x = pkbf2(cc[8*half+0], cc[8*half+1]);
                    wv.y = pkbf2(cc[8*half+2], cc[8*half+3]);
                    wv.z = pkbf2(cc[8*half+4], cc[8*half+5]);
                    wv.w = pkbf2(cc[8*half+6], cc[8*half+7]);
                    *(u4v*)&su.s.Vt[dd + e][jh2 * 16 + 8 * half] = wv;
                }
            }
        }
        if (tid < TJ) a_s[tid] = a_ws[(size_t)bh * Ss + J0 + tid];
        __syncthreads();

        // ---- QK: S^T tile [16j x 16i] per wave ----
        f4v c = {0.f, 0.f, 0.f, 0.f};
#pragma unroll
        for (int ks = 0; ks < 8; ks++) {
            s8v af = *(const s8v*)&su.s.K[jh * 16 + lm][ks * 32 + q4 * 8];
            c = __builtin_amdgcn_mfma_f32_16x16x32_bf16(af, qf[ks], c, 0, 0, 0);
        }
        {
            const int jb = jh * 16 + q4 * 4;
            const int ig = I0 + ih * 16 + lm;
            float p[4];
            float rsum = 0.f;
#pragma unroll
            for (int r = 0; r < 4; r++) {
                int jg = J0 + jb + r;
                float pv = 0.f;
                if (jg <= ig) pv = c[r] * inv_sqrt_dh * __expf(a_s[jb + r] - Mi);
                p[r] = pv; rsum += pv;
            }
            unsigned lo = pkbf2(p[0], p[1]), hi2 = pkbf2(p[2], p[3]);
            union { u16x4 v; unsigned u2[2]; } pw;
            pw.u2[0] = lo; pw.u2[1] = hi2;
            *(u16x4*)&su.s.P[ih * 16 + lm][jb] = pw.v;
            rsum += __shfl_xor(rsum, 16);
            rsum += __shfl_xor(rsum, 32);
            rs_acc += rsum;
        }
        __syncthreads();

        // ---- PV: H[32 x 256] += P[32 x 32] · V[32 x 256] ----
        const int n0 = w * 64;
#pragma unroll
        for (int ks2 = 0; ks2 < 32; ks2 += 16) {
            s8v pa  = *(const s8v*)&su.s.P[m5][ks2 + hl * 8];
            s8v vb0 = *(const s8v*)&su.s.Vt[n0 + m5][ks2 + hl * 8];
            s8v vb1 = *(const s8v*)&su.s.Vt[n0 + 32 + m5][ks2 + hl * 8];
            acc0 = __builtin_amdgcn_mfma_f32_32x32x16_bf16(pa, vb0, acc0, 0, 0, 0);
            acc1 = __builtin_amdgcn_mfma_f32_32x32x16_bf16(pa, vb1, acc1, 0, 0, 0);
        }
    }

    // ---- epilogue ----
    if (lane < 16) rs_s[jh][ih * 16 + lm] = rs_acc;
    __syncthreads();

    if (SPLIT) {
        if (tid < TI)
            rsbuf[(size_t)seg * BH * Ss + (size_t)bh * Ss + I0 + tid] = rs_s[0][tid] + rs_s[1][tid];
        // dump raw fp32 partial H
#pragma unroll
        for (int nt = 0; nt < 2; nt++) {
#pragma unroll
            for (int r = 0; r < 16; r++) {
                int m = (r & 3) + 8 * (r >> 2) + 4 * hl;
                su.Hs[m][w * 64 + nt * 32 + m5] = nt ? acc1[r] : acc0[r];
            }
        }
        __syncthreads();
        {
            int i = tid >> 3, sg = tid & 7;
            float* orow = Hdst + ((size_t)(b * Ss + I0 + i)) * Ee + hoff;
#pragma unroll
            for (int c4 = 0; c4 < 8; c4++) {
                int d = sg * 32 + c4 * 4;
                *(float4*)(orow + d) = *(const float4*)&su.Hs[i][d];
            }
        }
        return;
    }

    // non-split: full normalize + group-norm epilogue
    if (tid < TI) {
        float r = rs_s[0][tid] + rs_s[1][tid];
        float nfv = nf_ws[(size_t)bh * Ss + I0 + tid];
        float n = fmaxf(fabsf(r), nfv) + 1e-8f;
        inv_s[tid] = 1.f / n;
    }
    __syncthreads();
#pragma unroll
    for (int nt = 0; nt < 2; nt++) {
#pragma unroll
        for (int r = 0; r < 16; r++) {
            int m = (r & 3) + 8 * (r >> 2) + 4 * hl;
            float x = (nt ? acc1[r] : acc0[r]) * inv_s[m];
            su.Hs[m][w * 64 + nt * 32 + m5] = x;
        }
    }
    __syncthreads();
    {
        int i = tid >> 3, sg = tid & 7;
        float sx = 0.f, sq = 0.f;
#pragma unroll
        for (int c4 = 0; c4 < 8; c4++) {
            float4 hv = *(const float4*)&su.Hs[i][sg * 32 + c4 * 4];
            sx += hv.x + hv.y + hv.z + hv.w;
            sq += hv.x*hv.x + hv.y*hv.y + hv.z*hv.z + hv.w*hv.w;
        }
        sx += __shfl_xor(sx, 1); sq += __shfl_xor(sq, 1);
        sx += __shfl_xor(sx, 2); sq += __shfl_xor(sq, 2);
        sx += __shfl_xor(sx, 4); sq += __shfl_xor(sq, 4);
        if (sg == 0) {
            float mean = sx * (1.f / DHh);
            float var  = sq * (1.f / DHh) - mean * mean;
            mean_s[i] = mean;
            rstd_s[i] = rsqrtf(var + 1e-5f);
        }
    }
    __syncthreads();
    {
        int i = tid >> 3, sg = tid & 7;
        float mean = mean_s[i], rstd = rstd_s[i];
        float* orow = outF + ((size_t)(b * Ss + I0 + i)) * Ee + hoff;
        const float* ow = out_w + hoff;
#pragma unroll
        for (int c4 = 0; c4 < 8; c4++) {
            int d = sg * 32 + c4 * 4;
            float4 hv = *(const float4*)&su.Hs[i][d];
            float4 w4 = *(const float4*)&ow[d];
            float4 o;
            o.x = (hv.x - mean) * rstd * (1.f + w4.x);
            o.y = (hv.y - mean) * rstd * (1.f + w4.y);
            o.z = (hv.z - mean) * rstd * (1.f + w4.z);
            o.w = (hv.w - mean) * rstd * (1.f + w4.w);
            *(float4*)(orow + d) = o;
        }
    }
}

// ---------------------------------------------------------------------------
// Kernel 4 (SPLIT path): combine partials, normalize, group-norm. 1 wave/row.
// ---------------------------------------------------------------------------
__global__ __launch_bounds__(256) void combine_kernel(
    const float* __restrict__ Hb, const float* __restrict__ rsbuf,
    const float* __restrict__ nf_ws, const float* __restrict__ out_w,
    float* __restrict__ outF)
{
    int rid = blockIdx.x * 4 + (threadIdx.x >> 6);   // row over BH*S
    int lane = threadIdx.x & 63;
    int bh = rid >> 11, s = rid & 2047;
    int b = bh >> 2, h = bh & 3;
    size_t base = ((size_t)(b * Ss + s)) * Ee + (size_t)h * DHh + lane * 4;
    float4 ha = *(const float4*)(outF + base);
    float4 hb = *(const float4*)(Hb + base);
    float rs = rsbuf[(size_t)bh * Ss + s] + rsbuf[(size_t)BH * Ss + (size_t)bh * Ss + s];
    float nfv = nf_ws[(size_t)bh * Ss + s];
    float invn = 1.f / (fmaxf(fabsf(rs), nfv) + 1e-8f);
    float4 x;
    x.x = (ha.x + hb.x) * invn;
    x.y = (ha.y + hb.y) * invn;
    x.z = (ha.z + hb.z) * invn;
    x.w = (ha.w + hb.w) * invn;
    float sx = x.x + x.y + x.z + x.w;
    float sq = x.x*x.x + x.y*x.y + x.z*x.z + x.w*x.w;
#pragma unroll
    for (int off = 1; off < 64; off <<= 1) {
        sx += __shfl_xor(sx, off);
        sq += __shfl_xor(sq, off);
    }
    float mean = sx * (1.f / DHh);
    float var  = sq * (1.f / DHh) - mean * mean;
    float rstd = rsqrtf(var + 1e-5f);
    float4 w4 = *(const float4*)(out_w + (size_t)h * DHh + lane * 4);
    float4 o;
    o.x = (x.x - mean) * rstd * (1.f + w4.x);
    o.y = (x.y - mean) * rstd * (1.f + w4.y);
    o.z = (x.z - mean) * rstd * (1.f + w4.z);
    o.w = (x.w - mean) * rstd * (1.f + w4.w);
    *(float4*)(outF + base) = o;
}

// ---------------------------------------------------------------------------
extern "C" void kernel_launch(void* const* d_in, const int* in_sizes, int n_in,
                              void* d_out, int out_size, void* d_ws, size_t ws_size,
                              hipStream_t stream) {
    const float* q   = (const float*)d_in[0];
    const float* k   = (const float*)d_in[1];
    const float* v   = (const float*)d_in[2];
    const float* igw = (const float*)d_in[3];
    const float* igb = (const float*)d_in[4];
    const float* fgw = (const float*)d_in[5];
    const float* fgb = (const float*)d_in[6];
    const float* ow  = (const float*)d_in[7];
    float* out = (float*)d_out;

    float* ws = (float*)d_ws;
    float* ig = ws;                     // BH*S floats each
    float* fg = ws + 16384;
    float* aa = ws + 32768;
    float* MM = ws + 49152;
    float* nf = ws + 65536;
    float* rsb   = ws + 81920;          // 2 * BH * S floats
    float* Hpart = ws + 114688;         // B*S*E floats = 16 MB

    const size_t need = (size_t)(114688 + Bb * Ss * Ee) * 4;
    const bool split = ws_size >= need;

    gates_kernel<<<Bb * Ss, 256, 0, stream>>>(q, k, v, igw, igb, fgw, fgb, ig, fg);
    scan_kernel<<<BH, 256, 0, stream>>>(ig, fg, aa, MM, nf);
    if (split) {
        mlstm_main<true><<<1024, 256, 0, stream>>>(q, k, v, aa, MM, nf, ow, out, Hpart, rsb);
        combine_kernel<<<BH * Ss / 4, 256, 0, stream>>>(Hpart, rsb, nf, ow, out);
    } else {
        mlstm_main<false><<<512, 256, 0, stream>>>(q, k, v, aa, MM, nf, ow, out, Hpart, rsb);
    }
}